// Round 11
// baseline (65.764 us; speedup 1.0000x reference)
//
#include <hip/hip_runtime.h>

// RippleLinear, single-dispatch all-register poly-GEMM, 1024-thread blocks.
//   out[b,o] = sum_i amp[i,o]*sin(x[b,i]*f[i,o] + p[i,o]) + bias0[o]
// R15. History: R5 75.8 | R12 70.2 | R13 68.8 | R14(BM=128,512thr) 65.8.
// Decomposition: base ~49.8us; R14 exec ~16us vs ~4us issue model.
// The realism factor tracks occupancy (R12 @4waves/SIMD: 1.8x; R13/R14
// @2waves/SIMD: 4x). R14 is GRID-limited: 256 blocks x 8 waves = exactly
// 1 block/CU = 2 waves/SIMD regardless of VGPR. Fix: same grid, 1024-thr
// blocks (16 waves) -> 4 waves/SIMD; per-thread state+prep HALVED:
//   wm in {0,1} (64-row half) x kh in 0..7 (32-i chunk);
//   A-state 4 subtiles x 8 = 32 elems (+powers) = 64 regs; B-state 8 trig
//   pairs = 24 regs; acc 16; ~124 total <= 128 cap @ launch_bounds(1024,4).
//   Per j: 48 fmul + 40 cvt + 4 MFMA. 8-way kh-reduce (60.5KB LDS).
// Rounding points bit-identical to R14 (f32 power chain, scalar RTN cvt,
// j=0..8, f32 reduce) -> absmax must stay exactly 0.001953125.
// Prediction: exec 16 -> 8-10us => dur ~58-62. Forks: ~65 neutral =>
// occupancy theory dead, near floor; >70 => spill; absmax shift => bug.

typedef _Float16 f16;
typedef _Float16 f16x8 __attribute__((ext_vector_type(8)));
typedef float f32x4 __attribute__((ext_vector_type(4)));

constexpr int IN_F  = 256;
constexpr int OUT_F = 256;
constexpr int BROWS = 2048;
constexpr int BM = 128, BN = 16;
constexpr int RPAD = 17;             // red row pad -> spread banks

#define XS 0.25f
#define INV2PI 0.15915494309189535f
#define MFMA16 __builtin_amdgcn_mfma_f32_16x16x32_f16

__device__ __forceinline__ f16x8 cvt8(const float* v) {
    f16x8 r;
#pragma unroll
    for (int e = 0; e < 8; ++e) r[e] = (f16)v[e];   // scalar RTN, same as R9-R14
    return r;
}

__global__ __launch_bounds__(1024, 4) void fused(
    const float* __restrict__ x,      // (2048, 256)
    const float* __restrict__ w,      // (256, 256, 2)
    const float* __restrict__ bias,   // (257, 256)
    float* __restrict__ out)          // (2048, 256)
{
    __shared__ float red[7][BM][RPAD];    // 60.9 KB kh-reduction buffer

    const int t  = threadIdx.x;       // 0..1023 (16 waves)
    const int n0 = (blockIdx.x & 15) * BN;
    const int m0 = (blockIdx.x >> 4) * BM;
    const int l  = t & 63;
    const int wv = t >> 6;            // 0..15
    const int wm = wv & 1;            // m-half (64 rows)
    const int kh = wv >> 1;           // i-chunk of 32 (0..7)
    const int oc = l & 15;            // frag spatial index
    const int fk = (l >> 4) * 8;      // lane k-offset within the 32-chunk
    const int o  = n0 + oc;
    const int i0 = kh * 32 + fk;      // lane i-base (8 consecutive i)

    // ---------------- B-state: 8 (i,o) pairs, registers only ----------------
    float gs[8], gc[8], f4sq[8];
#pragma unroll
    for (int e = 0; e < 8; ++e) {
        const int i = i0 + e;
        const float2 w2 = ((const float2*)w)[i * OUT_F + o];   // (amp, f)
        const float p   = bias[(1 + i) * OUT_F + o];
        const float sp  = __builtin_amdgcn_sinf(p * INV2PI);
        const float cp  = __builtin_amdgcn_cosf(p * INV2PI);
        const float f4  = 4.0f * w2.y;
        gs[e]   = w2.x * sp;          // j=0:  amp*sin(p)
        gc[e]   = (w2.x * cp) * f4;   // j=1:  amp*cos(p)*(4f)
        f4sq[e] = f4 * f4;
    }

    // ---------------- A-state: 4 m-subtiles x 8 running powers (f32) ----------------
    const int rbase = m0 + wm * 64 + oc;         // subtile s adds s*16
    float xq[4][8], xp[4][8];
#pragma unroll
    for (int s = 0; s < 4; ++s) {
        const float* xr = x + (size_t)(rbase + s * 16) * IN_F;
        const f32x4 a0 = *(const f32x4*)(xr + i0);
        const f32x4 a1 = *(const f32x4*)(xr + i0 + 4);
#pragma unroll
        for (int e = 0; e < 4; ++e) {
            xq[s][e]     = a0[e] * XS;
            xq[s][4 + e] = a1[e] * XS;
        }
    }

    f32x4 acc[4];
#pragma unroll
    for (int s = 0; s < 4; ++s) acc[s] = (f32x4){0.f, 0.f, 0.f, 0.f};

    // ---- j = 0: A == 1 ----
    {
        f16x8 ones;
#pragma unroll
        for (int e = 0; e < 8; ++e) ones[e] = (f16)1.0f;
        const f16x8 bf = cvt8(gs);
#pragma unroll
        for (int s = 0; s < 4; ++s) acc[s] = MFMA16(ones, bf, acc[s], 0, 0, 0);
    }
    // ---- j = 1: A = x/4 ----
    {
        const f16x8 bf = cvt8(gc);
#pragma unroll
        for (int s = 0; s < 4; ++s) acc[s] = MFMA16(cvt8(xq[s]), bf, acc[s], 0, 0, 0);
    }
    // ---- j = 2..8: advance, 4 MFMAs, no memory, no barriers ----
    const float RJ[9] = {0.f, 0.f, -0.5f, -1.f/6.f, -1.f/12.f, -1.f/20.f,
                         -1.f/30.f, -1.f/42.f, -1.f/56.f};
#pragma unroll
    for (int j = 2; j <= 8; ++j) {
#pragma unroll
        for (int s = 0; s < 4; ++s) {
#pragma unroll
            for (int n = 0; n < 8; ++n) {
                if (j == 2) xp[s][n] = xq[s][n] * xq[s][n];
                else        xp[s][n] *= xq[s][n];
            }
        }
        f16x8 bf;
        if (j & 1) {
#pragma unroll
            for (int n = 0; n < 8; ++n) gc[n] = (gc[n] * f4sq[n]) * RJ[j];
            bf = cvt8(gc);
        } else {
#pragma unroll
            for (int n = 0; n < 8; ++n) gs[n] = (gs[n] * f4sq[n]) * RJ[j];
            bf = cvt8(gs);
        }
#pragma unroll
        for (int s = 0; s < 4; ++s) acc[s] = MFMA16(cvt8(xp[s]), bf, acc[s], 0, 0, 0);
    }

    // ---------------- kh-reduce + epilogue (C/D: col=l&15, row=(l>>4)*4+r) ----------------
    if (kh > 0) {
#pragma unroll
        for (int s = 0; s < 4; ++s)
#pragma unroll
            for (int r = 0; r < 4; ++r)
                red[kh - 1][wm * 64 + s * 16 + (l >> 4) * 4 + r][oc] = acc[s][r];
    }
    __syncthreads();
    if (kh == 0) {
        const float b0v = bias[o];    // bias row 0
#pragma unroll
        for (int s = 0; s < 4; ++s) {
#pragma unroll
            for (int r = 0; r < 4; ++r) {
                const int rr = wm * 64 + s * 16 + (l >> 4) * 4 + r;
                float v = acc[s][r] + b0v;
#pragma unroll
                for (int q = 0; q < 7; ++q) v += red[q][rr][oc];
                out[(size_t)(m0 + rr) * OUT_F + o] = v;
            }
        }
    }
}

extern "C" void kernel_launch(void* const* d_in, const int* in_sizes, int n_in,
                              void* d_out, int out_size, void* d_ws, size_t ws_size,
                              hipStream_t stream) {
    const float* x      = (const float*)d_in[0];
    const float* weight = (const float*)d_in[1];
    const float* bias   = (const float*)d_in[2];
    float* out          = (float*)d_out;

    fused<<<dim3((BROWS / BM) * (OUT_F / BN)), dim3(1024), 0, stream>>>(
        x, weight, bias, out);
}